// Round 4
// baseline (675.218 us; speedup 1.0000x reference)
//
#include <hip/hip_runtime.h>
#include <math.h>

#define B_    4
#define L_    4092
#define H_    8
#define DM    512
#define WS_   12
#define NW    681
#define NC    682            // 6-row output chunks per (b,h); L = 6*682
#define EPS_  1e-5f
#define Z_ELEMS (B_*L_*DM)   // 8,380,416
#define NQUAD 32736          // 130,944 rows / 4

typedef unsigned short u16;
typedef __attribute__((ext_vector_type(8))) unsigned short ushort8v;

__device__ __forceinline__ u16 f2bf(float f) {
    union { float f; unsigned u; } x; x.f = f;
    unsigned u = x.u;
    return (u16)((u + 0x7FFFu + ((u >> 16) & 1u)) >> 16);
}
__device__ __forceinline__ float bf2f(u16 h) {
    union { unsigned u; float f; } x; x.u = ((unsigned)h) << 16; return x.f;
}

// ---------------------------------------------------------------------------
// K1: pure-fp32 VALU projection GEMM.
// Round-3 rocprof: 90 µs, VALUBusy 63%, HBM 19%, conflicts 0 -> the LDS
// X-broadcast (64 ds_read_b128 + ds_write->lgkm chain per quad) is the
// residual cost. Fix: X read via WAVE-UNIFORM global loads (1 line/instr,
// scalarizable); W staged TRANSPOSED in LDS once per block (coalesced read,
// conflict-free write) then pulled into 64 VGPRs once per wave. Inner loop
// is pure FMA: no DS ops, no barriers. Q,K stored fp32 (exact score chain);
// V stored bf16. Accumulation order identical to round 3 (bit-identical out).
// ---------------------------------------------------------------------------
__global__ __launch_bounds__(256, 4) void proj_kernel(
    const float* __restrict__ q, const float* __restrict__ k, const float* __restrict__ v,
    const float* __restrict__ Wq, const float* __restrict__ Wk, const float* __restrict__ Wv,
    float* __restrict__ Qf, float* __restrict__ Kf, u16* __restrict__ Vh)
{
    __shared__ float Wt[64][65];   // transposed W, pad 65 -> 2-way (free) reads

    const int tensor = blockIdx.y;
    const float* __restrict__ X = (tensor == 0) ? q  : (tensor == 1) ? k  : v;
    const float* __restrict__ W = (tensor == 0) ? Wq : (tensor == 1) ? Wk : Wv;
    float* __restrict__ Yf      = (tensor == 0) ? Qf : Kf;
    const bool isV = (tensor == 2);

    const int t = threadIdx.x, lane = t & 63, wv = t >> 6;

    // stage W transposed: coalesced global read, conflict-free LDS write
    for (int i = t; i < 4096; i += 256) {
        const int r = i >> 6, cidx = i & 63;   // W[r][cidx], row-major
        Wt[cidx][r] = W[i];
    }
    __syncthreads();

    // W row `lane` -> 64 VGPRs, once per wave (2-way bank = free)
    float wr[64];
    #pragma unroll
    for (int d = 0; d < 64; ++d) wr[d] = Wt[d][lane];

    const int waveId = blockIdx.x * 4 + wv;      // 0..1023
    for (int qd = waveId; qd < NQUAD; qd += 1024) {
        const int rbase = qd * 4;                // quads never cross bh (4092%4==0)
        const int bh = rbase / L_;
        const int l0 = rbase - bh * L_;
        const int b = bh >> 3, h = bh & 7;
        // wave-uniform row base; consecutive l stride = H_*64 = 512 floats
        const float* xr = X + (((size_t)b * L_ + l0) * H_ + h) * 64;

        float acc0 = 0.f, acc1 = 0.f, acc2 = 0.f, acc3 = 0.f;
        #pragma unroll
        for (int d4 = 0; d4 < 16; ++d4) {
            const float4 x0 = *(const float4*)(xr + d4 * 4);            // uniform
            const float4 x1 = *(const float4*)(xr + 512 + d4 * 4);
            const float4 x2 = *(const float4*)(xr + 1024 + d4 * 4);
            const float4 x3 = *(const float4*)(xr + 1536 + d4 * 4);
            const float w0 = wr[4 * d4 + 0], w1 = wr[4 * d4 + 1];
            const float w2 = wr[4 * d4 + 2], w3 = wr[4 * d4 + 3];
            acc0 += x0.x*w0 + x0.y*w1 + x0.z*w2 + x0.w*w3;
            acc1 += x1.x*w0 + x1.y*w1 + x1.z*w2 + x1.w*w3;
            acc2 += x2.x*w0 + x2.y*w1 + x2.z*w2 + x2.w*w3;
            acc3 += x3.x*w0 + x3.y*w1 + x3.z*w2 + x3.w*w3;
        }

        const size_t orow = (size_t)rbase * 64 + lane;
        if (!isV) {
            Yf[orow]       = acc0;
            Yf[orow + 64]  = acc1;
            Yf[orow + 128] = acc2;
            Yf[orow + 192] = acc3;
        } else {
            Vh[orow]       = f2bf(acc0);
            Vh[orow + 64]  = f2bf(acc1);
            Vh[orow + 128] = f2bf(acc2);
            Vh[orow + 192] = f2bf(acc3);
        }
    }
}

// ---------------------------------------------------------------------------
// K2: fused window attention + overlap-add + residual + LayerNorm.
// Round-3 diagnosis: ~157 µs at ~3k cycles of VALU/block -> latency-bound:
// 73.7 KB LDS (2 blocks/CU) + a hard barrier right after staging serialized
// stage-latency -> compute. Fix: NO K/V staging at all — K(fp32)/V(bf16)
// read straight from global (per-instr only 4 distinct 64B addresses; all 18
// loads independent -> one latency per pass). LDS = 12.4 KB Xs only -> 4
// blocks/CU, waves run barrier-free until the LN exchange. OOB rows use
// clamped addresses; hasA/hasB masks already zero their weights.
// Arithmetic order identical to round 3 -> bit-identical output.
// ---------------------------------------------------------------------------
__global__ __launch_bounds__(512, 4) void attn_ln_kernel(
    const float* __restrict__ Qf, const float* __restrict__ Kf, const u16* __restrict__ Vh,
    const float* __restrict__ qres, const float* __restrict__ gamma,
    const float* __restrict__ beta, float* __restrict__ attn, float* __restrict__ z)
{
    __shared__ alignas(16) float Xs[6 * 516];    // 12.4 KB, stride 516

    const int c = blockIdx.x, b = blockIdx.y;
    const int t = threadIdx.x, lane = t & 63, h = t >> 6;
    const int qq = lane >> 2, ks = lane & 3;
    const int bh = b * 8 + h;
    const int lbase = c * 6 - 6;

    const bool hasA = (c < NW), hasB = (c > 0);     // block-uniform
    const float scale = (hasA && hasB) ? 0.5f : 1.0f;

    const float* Qb = Qf + (size_t)bh * L_ * 64;
    const float* Kb = Kf + (size_t)bh * L_ * 64;
    const u16*   Vb = Vh + (size_t)bh * L_ * 64;

    // Q segment for global row c*6+qq (zeros on invalid lanes -> s == 0, finite)
    float4 qs0, qs1, qs2, qs3;
    const int qmax = hasA ? 12 : 6;
    if (qq < qmax) {
        const float* qp = Qb + (size_t)(c * 6 + qq) * 64 + ks * 16;
        qs0 = *(const float4*)(qp);     qs1 = *(const float4*)(qp + 4);
        qs2 = *(const float4*)(qp + 8); qs3 = *(const float4*)(qp + 12);
    } else {
        qs0 = qs1 = qs2 = qs3 = make_float4(0.f, 0.f, 0.f, 0.f);
    }

    // --- unified dot pass: Q row (c*6+qq) vs K rows lbase..lbase+17 (global) ---
    float s[18];
    #pragma unroll
    for (int kt = 0; kt < 18; ++kt) {
        int l = lbase + kt;
        l = (l < 0) ? 0 : ((l >= L_) ? (L_ - 1) : l);   // clamp; masked later
        const float* kp = Kb + (size_t)l * 64 + ks * 16;
        const float4 k0 = *(const float4*)(kp);
        const float4 k1 = *(const float4*)(kp + 4);
        const float4 k2 = *(const float4*)(kp + 8);
        const float4 k3 = *(const float4*)(kp + 12);
        s[kt] = qs0.x*k0.x + qs0.y*k0.y + qs0.z*k0.z + qs0.w*k0.w
              + qs1.x*k1.x + qs1.y*k1.y + qs1.z*k1.z + qs1.w*k1.w
              + qs2.x*k2.x + qs2.y*k2.y + qs2.z*k2.z + qs2.w*k2.w
              + qs3.x*k3.x + qs3.y*k3.y + qs3.z*k3.z + qs3.w*k3.w;
    }
    // reduce partial dots over the 4 ks-lanes
    #pragma unroll
    for (int kt = 0; kt < 18; ++kt) {
        s[kt] += __shfl_xor(s[kt], 1);
        s[kt] += __shfl_xor(s[kt], 2);
    }

    // --- softmax A: window c, over s[6..17] ---
    float eA[12], invA = 0.f;
    if (hasA) {
        float mxA = s[6];
        #pragma unroll
        for (int j = 1; j < 12; ++j) mxA = fmaxf(mxA, s[6 + j]);
        float sumA = 0.f;
        #pragma unroll
        for (int j = 0; j < 12; ++j) { eA[j] = __expf((s[6 + j] - mxA) * 0.125f); sumA += eA[j]; }
        invA = 1.0f / sumA;
        if (ks == 0 && qq < 12) {
            float* ao = attn + ((size_t)bh * NW + c) * 144 + qq * 12;
            float4 a0, a1, a2;
            a0.x = eA[0]*invA; a0.y = eA[1]*invA;  a0.z = eA[2]*invA;  a0.w = eA[3]*invA;
            a1.x = eA[4]*invA; a1.y = eA[5]*invA;  a1.z = eA[6]*invA;  a1.w = eA[7]*invA;
            a2.x = eA[8]*invA; a2.y = eA[9]*invA;  a2.z = eA[10]*invA; a2.w = eA[11]*invA;
            *(float4*)(ao)     = a0;
            *(float4*)(ao + 4) = a1;
            *(float4*)(ao + 8) = a2;
        }
    } else {
        #pragma unroll
        for (int j = 0; j < 12; ++j) eA[j] = 0.f;
    }

    // --- softmax B: window c-1 (this Q row acts as its row qq+6), over s[0..11] ---
    float eB[12], invB = 0.f;
    if (hasB) {
        float mxB = s[0];
        #pragma unroll
        for (int j = 1; j < 12; ++j) mxB = fmaxf(mxB, s[j]);
        float sumB = 0.f;
        #pragma unroll
        for (int j = 0; j < 12; ++j) { eB[j] = __expf((s[j] - mxB) * 0.125f); sumB += eB[j]; }
        invB = 1.0f / sumB;
    } else {
        #pragma unroll
        for (int j = 0; j < 12; ++j) eB[j] = 0.f;
    }

    // --- fused PV over 18 rows with combined overlap-add weights (V global) ---
    float4 xo0 = make_float4(0.f,0.f,0.f,0.f), xo1 = xo0, xo2 = xo0, xo3 = xo0;
    if (qq < 6) {
        #pragma unroll
        for (int kt = 0; kt < 18; ++kt) {
            const float wa = (kt >= 6) ? eA[kt - 6] * invA : 0.f;
            const float wb = (kt < 12) ? eB[kt] * invB : 0.f;
            const float wk = scale * (wa + wb);
            int l = lbase + kt;
            l = (l < 0) ? 0 : ((l >= L_) ? (L_ - 1) : l);   // clamp; wk==0 there
            const u16* vp = Vb + (size_t)l * 64 + ks * 16;
            const ushort8v va = *(const ushort8v*)(vp);
            const ushort8v vb2 = *(const ushort8v*)(vp + 8);
            float4 v0, v1, v2, v3;
            v0.x = bf2f(va[0]);  v0.y = bf2f(va[1]);  v0.z = bf2f(va[2]);  v0.w = bf2f(va[3]);
            v1.x = bf2f(va[4]);  v1.y = bf2f(va[5]);  v1.z = bf2f(va[6]);  v1.w = bf2f(va[7]);
            v2.x = bf2f(vb2[0]); v2.y = bf2f(vb2[1]); v2.z = bf2f(vb2[2]); v2.w = bf2f(vb2[3]);
            v3.x = bf2f(vb2[4]); v3.y = bf2f(vb2[5]); v3.z = bf2f(vb2[6]); v3.w = bf2f(vb2[7]);
            xo0.x += wk*v0.x; xo0.y += wk*v0.y; xo0.z += wk*v0.z; xo0.w += wk*v0.w;
            xo1.x += wk*v1.x; xo1.y += wk*v1.y; xo1.z += wk*v1.z; xo1.w += wk*v1.w;
            xo2.x += wk*v2.x; xo2.y += wk*v2.y; xo2.z += wk*v2.z; xo2.w += wk*v2.w;
            xo3.x += wk*v3.x; xo3.y += wk*v3.y; xo3.z += wk*v3.z; xo3.w += wk*v3.w;
        }
        float* xp = Xs + qq * 516 + h * 64 + ks * 16;
        *(float4*)(xp)      = xo0;
        *(float4*)(xp + 4)  = xo1;
        *(float4*)(xp + 8)  = xo2;
        *(float4*)(xp + 12) = xo3;
    }
    __syncthreads();

    // --- LN: wave h (<6) handles chunk row h; lane covers 8 cols ---
    if (h < 6) {
        const int l = c * 6 + h;
        const int cc = lane * 8;
        float4 xa = *(const float4*)(Xs + h * 516 + cc);
        float4 xb = *(const float4*)(Xs + h * 516 + cc + 4);
        const float* qr = qres + ((size_t)b * L_ + l) * DM + cc;
        const float4 ra  = *(const float4*)qr;
        const float4 rb2 = *(const float4*)(qr + 4);
        xa.x += ra.x;  xa.y += ra.y;  xa.z += ra.z;  xa.w += ra.w;
        xb.x += rb2.x; xb.y += rb2.y; xb.z += rb2.z; xb.w += rb2.w;

        float s1 = xa.x + xa.y + xa.z + xa.w + xb.x + xb.y + xb.z + xb.w;
        float s2 = xa.x*xa.x + xa.y*xa.y + xa.z*xa.z + xa.w*xa.w
                 + xb.x*xb.x + xb.y*xb.y + xb.z*xb.z + xb.w*xb.w;
        #pragma unroll
        for (int off = 1; off < 64; off <<= 1) {
            s1 += __shfl_xor(s1, off, 64);
            s2 += __shfl_xor(s2, off, 64);
        }
        const float mu  = s1 * (1.0f / 512.0f);
        const float var = s2 * (1.0f / 512.0f) - mu * mu;
        const float inv = 1.0f / sqrtf(var + EPS_);

        const float4 ga = *(const float4*)(gamma + cc);
        const float4 gb = *(const float4*)(gamma + cc + 4);
        const float4 ba = *(const float4*)(beta + cc);
        const float4 bb = *(const float4*)(beta + cc + 4);
        float4 oa, ob;
        oa.x = (xa.x - mu) * inv * ga.x + ba.x;
        oa.y = (xa.y - mu) * inv * ga.y + ba.y;
        oa.z = (xa.z - mu) * inv * ga.z + ba.z;
        oa.w = (xa.w - mu) * inv * ga.w + ba.w;
        ob.x = (xb.x - mu) * inv * gb.x + bb.x;
        ob.y = (xb.y - mu) * inv * gb.y + bb.y;
        ob.z = (xb.z - mu) * inv * gb.z + bb.z;
        ob.w = (xb.w - mu) * inv * gb.w + bb.w;
        float* zp = z + ((size_t)b * L_ + l) * DM + cc;
        *(float4*)zp = oa;
        *(float4*)(zp + 4) = ob;
    }
}

extern "C" void kernel_launch(void* const* d_in, const int* in_sizes, int n_in,
                              void* d_out, int out_size, void* d_ws, size_t ws_size,
                              hipStream_t stream) {
    const float* q     = (const float*)d_in[0];
    const float* k     = (const float*)d_in[1];
    const float* v     = (const float*)d_in[2];
    const float* Wq    = (const float*)d_in[3];
    const float* Wk    = (const float*)d_in[4];
    const float* Wv    = (const float*)d_in[5];
    const float* gamma = (const float*)d_in[6];
    const float* beta  = (const float*)d_in[7];

    float* z    = (float*)d_out;
    float* attn = (float*)d_out + Z_ELEMS;

    // Workspace: Qf fp32 (33.5 MB) + Kf fp32 (33.5 MB) + Vh bf16 (16.8 MB)
    const size_t plane = (size_t)B_ * H_ * L_ * 64;   // 8,380,416 elements
    float* Qf = (float*)d_ws;
    float* Kf = Qf + plane;
    u16*  Vh  = (u16*)(Kf + plane);

    proj_kernel<<<dim3(256, 3, 1), 256, 0, stream>>>(q, k, v, Wq, Wk, Wv, Qf, Kf, Vh);
    attn_ln_kernel<<<dim3(NC, B_), 512, 0, stream>>>(Qf, Kf, Vh, q, gamma, beta, attn, z);
}

// Round 5
// 254.240 us; speedup vs baseline: 2.6558x; 2.6558x over previous
//
#include <hip/hip_runtime.h>
#include <math.h>

#define B_    4
#define L_    4092
#define H_    8
#define DM    512
#define WS_   12
#define NW    681
#define NC    682            // 6-row output chunks per (b,h); L = 6*682
#define EPS_  1e-5f
#define Z_ELEMS (B_*L_*DM)   // 8,380,416
#define NQUAD 32736          // 130,944 rows / 4

typedef unsigned short u16;

__device__ __forceinline__ u16 f2bf(float f) {
    union { float f; unsigned u; } x; x.f = f;
    unsigned u = x.u;
    return (u16)((u + 0x7FFFu + ((u >> 16) & 1u)) >> 16);
}
__device__ __forceinline__ float bf2f(u16 h) {
    union { unsigned u; float f; } x; x.u = ((unsigned)h) << 16; return x.f;
}

// ---------------------------------------------------------------------------
// K1: pure-fp32 VALU projection GEMM (R3 structure + serialization fixes).
// R3 measured 90 µs / VALUBusy 63%: residual cost was (a) per-wave strided W
// gather (64 instrs x 64 lines) and (b) single-buffered Xw: ds_write -> wait
// -> 64 ds_read -> WAR -> next write, with the next global X load issued only
// after. Fix: W via coalesced LDS transpose (R4's proven piece); X slices
// DOUBLE-BUFFERED with the next quad's global load prefetched before compute.
// R4's lesson applied: X broadcast stays in LDS (uniform-address ds_read is a
// true free broadcast; uniform global loads are full-latency VMEM).
// Accumulation order identical to R3 -> bit-identical planes.
// ---------------------------------------------------------------------------
__device__ __forceinline__ float4 load_x4(const float* __restrict__ X,
                                          int qd, int li, int lc) {
    const int rbase = qd * 4;                    // quads never cross bh (4092%4==0)
    const int bh = rbase / L_;
    const int l0 = rbase - bh * L_;
    const int b = bh >> 3, h = bh & 7;
    return *(const float4*)(X + (((size_t)b * L_ + (l0 + li)) * H_ + h) * 64 + lc);
}

__global__ __launch_bounds__(256) void proj_kernel(
    const float* __restrict__ q, const float* __restrict__ k, const float* __restrict__ v,
    const float* __restrict__ Wq, const float* __restrict__ Wk, const float* __restrict__ Wv,
    float* __restrict__ Qf, float* __restrict__ Kf, u16* __restrict__ Vh)
{
    __shared__ float Wt[64][65];          // transposed W (padded)
    __shared__ float Xw[4][2][4][64];     // wave-private double-buffered slices

    const int tensor = blockIdx.y;
    const float* __restrict__ X = (tensor == 0) ? q  : (tensor == 1) ? k  : v;
    const float* __restrict__ W = (tensor == 0) ? Wq : (tensor == 1) ? Wk : Wv;
    float* __restrict__ Yf      = (tensor == 0) ? Qf : Kf;
    const bool isV = (tensor == 2);

    const int t = threadIdx.x, lane = t & 63, wv = t >> 6;

    // stage W transposed: coalesced global read, conflict-free LDS write
    for (int i = t; i < 4096; i += 256)
        Wt[i & 63][i >> 6] = W[i];
    __syncthreads();

    // W row `lane` -> 64 VGPRs, once per wave
    float wr[64];
    #pragma unroll
    for (int d = 0; d < 64; ++d) wr[d] = Wt[d][lane];

    const int li = lane >> 4;          // which quad-row this lane stages
    const int lc = (lane & 15) * 4;    // col

    const int waveId = blockIdx.x * 4 + wv;      // 0..2047
    int cur = 0;
    if (waveId < NQUAD) {                        // always true (2048 <= 32736)
        const float4 x0 = load_x4(X, waveId, li, lc);
        *(float4*)&Xw[wv][0][li][lc] = x0;
    }
    for (int qd = waveId; qd < NQUAD; qd += 2048) {
        const int qn = qd + 2048;
        const bool pf = (qn < NQUAD);            // wave-uniform
        float4 xn = make_float4(0.f, 0.f, 0.f, 0.f);
        if (pf) xn = load_x4(X, qn, li, lc);     // prefetch: VMEM in flight

        float acc0 = 0.f, acc1 = 0.f, acc2 = 0.f, acc3 = 0.f;
        #pragma unroll
        for (int d4 = 0; d4 < 16; ++d4) {
            const float4 x0 = *(const float4*)&Xw[wv][cur][0][d4 * 4];  // uniform addr
            const float4 x1 = *(const float4*)&Xw[wv][cur][1][d4 * 4];
            const float4 x2 = *(const float4*)&Xw[wv][cur][2][d4 * 4];
            const float4 x3 = *(const float4*)&Xw[wv][cur][3][d4 * 4];
            const float w0 = wr[4 * d4 + 0], w1 = wr[4 * d4 + 1];
            const float w2 = wr[4 * d4 + 2], w3 = wr[4 * d4 + 3];
            acc0 += x0.x*w0 + x0.y*w1 + x0.z*w2 + x0.w*w3;
            acc1 += x1.x*w0 + x1.y*w1 + x1.z*w2 + x1.w*w3;
            acc2 += x2.x*w0 + x2.y*w1 + x2.z*w2 + x2.w*w3;
            acc3 += x3.x*w0 + x3.y*w1 + x3.z*w2 + x3.w*w3;
        }

        const size_t orow = (size_t)(qd * 4) * 64 + lane;
        if (!isV) {
            Yf[orow]       = acc0;
            Yf[orow + 64]  = acc1;
            Yf[orow + 128] = acc2;
            Yf[orow + 192] = acc3;
        } else {
            Vh[orow]       = f2bf(acc0);
            Vh[orow + 64]  = f2bf(acc1);
            Vh[orow + 128] = f2bf(acc2);
            Vh[orow + 192] = f2bf(acc3);
        }

        if (pf) {                                  // write-behind into other buffer
            *(float4*)&Xw[wv][cur ^ 1][li][lc] = xn;
            cur ^= 1;
        }
    }
}

// ---------------------------------------------------------------------------
// K2a: fused window attention + overlap-add (NO LayerNorm -> no 8-head
// coupling). Block = 256 threads = 4 heads, grid (NC, B, 2). LDS = K fp32 +
// V fp32 for 4 heads = 36.9 KB -> 4 blocks/CU (2x R3's residency), ONE
// barrier. Combined 6x(4x64) chunk rows written fp32 into the z buffer
// (acts as Xout; K2b rewrites it in place). Dot/softmax/PV expressions and
// order copied verbatim from R3 -> bit-identical.
// ---------------------------------------------------------------------------
__global__ __launch_bounds__(256, 4) void attn_kernel(
    const float* __restrict__ Qf, const float* __restrict__ Kf, const u16* __restrict__ Vh,
    float* __restrict__ attn, float* __restrict__ xout)
{
    __shared__ alignas(16) float Ks[4][18][64];   // 18.4 KB
    __shared__ alignas(16) float Vs[4][18][64];   // 18.4 KB

    const int c = blockIdx.x, b = blockIdx.y, hg = blockIdx.z;
    const int t = threadIdx.x, lane = t & 63, w = t >> 6;   // w = head-in-group
    const int h = hg * 4 + w;
    const int qq = lane >> 2, ks = lane & 3;
    const int bh = b * 8 + h;
    const int lbase = c * 6 - 6;

    // --- stage K (fp32) + V (bf16->fp32) for 4 heads, zero-filling OOB rows ---
    for (int i = t; i < 1152; i += 256) {          // 1152 = 4 heads * 18 rows * 16 float4
        const int hh  = i / 288;
        const int rem = i - hh * 288;
        const int rr  = rem >> 4;
        const int cc  = (rem & 15) * 4;
        const int l = lbase + rr;
        float4 kf4 = make_float4(0.f, 0.f, 0.f, 0.f);
        float4 vf4 = make_float4(0.f, 0.f, 0.f, 0.f);
        if (l >= 0 && l < L_) {
            const size_t base = ((size_t)(b * 8 + hg * 4 + hh) * L_ + l) * 64 + cc;
            kf4 = *(const float4*)(Kf + base);
            const ushort4 u4 = *(const ushort4*)(Vh + base);
            vf4.x = bf2f(u4.x); vf4.y = bf2f(u4.y); vf4.z = bf2f(u4.z); vf4.w = bf2f(u4.w);
        }
        *(float4*)&Ks[hh][rr][cc] = kf4;
        *(float4*)&Vs[hh][rr][cc] = vf4;
    }
    __syncthreads();

    const bool hasA = (c < NW), hasB = (c > 0);     // block-uniform
    const float scale = (hasA && hasB) ? 0.5f : 1.0f;

    // Q segment for global row c*6+qq (zeros on invalid lanes -> s == 0, finite)
    float4 qs0, qs1, qs2, qs3;
    const int qmax = hasA ? 12 : 6;
    if (qq < qmax) {
        const float* qp = Qf + ((size_t)bh * L_ + (c * 6 + qq)) * 64 + ks * 16;
        qs0 = *(const float4*)(qp);     qs1 = *(const float4*)(qp + 4);
        qs2 = *(const float4*)(qp + 8); qs3 = *(const float4*)(qp + 12);
    } else {
        qs0 = qs1 = qs2 = qs3 = make_float4(0.f, 0.f, 0.f, 0.f);
    }

    // --- unified dot pass: Q row (c*6+qq) vs all 18 staged K rows ---
    float s[18];
    #pragma unroll
    for (int kt = 0; kt < 18; ++kt) {
        const float* kp = &Ks[w][kt][ks * 16];
        const float4 k0 = *(const float4*)(kp);
        const float4 k1 = *(const float4*)(kp + 4);
        const float4 k2 = *(const float4*)(kp + 8);
        const float4 k3 = *(const float4*)(kp + 12);
        s[kt] = qs0.x*k0.x + qs0.y*k0.y + qs0.z*k0.z + qs0.w*k0.w
              + qs1.x*k1.x + qs1.y*k1.y + qs1.z*k1.z + qs1.w*k1.w
              + qs2.x*k2.x + qs2.y*k2.y + qs2.z*k2.z + qs2.w*k2.w
              + qs3.x*k3.x + qs3.y*k3.y + qs3.z*k3.z + qs3.w*k3.w;
    }
    // reduce partial dots over the 4 ks-lanes
    #pragma unroll
    for (int kt = 0; kt < 18; ++kt) {
        s[kt] += __shfl_xor(s[kt], 1);
        s[kt] += __shfl_xor(s[kt], 2);
    }

    // --- softmax A: window c, over s[6..17] ---
    float eA[12], invA = 0.f;
    if (hasA) {
        float mxA = s[6];
        #pragma unroll
        for (int j = 1; j < 12; ++j) mxA = fmaxf(mxA, s[6 + j]);
        float sumA = 0.f;
        #pragma unroll
        for (int j = 0; j < 12; ++j) { eA[j] = __expf((s[6 + j] - mxA) * 0.125f); sumA += eA[j]; }
        invA = 1.0f / sumA;
        if (ks == 0 && qq < 12) {
            float* ao = attn + ((size_t)bh * NW + c) * 144 + qq * 12;
            float4 a0, a1, a2;
            a0.x = eA[0]*invA; a0.y = eA[1]*invA;  a0.z = eA[2]*invA;  a0.w = eA[3]*invA;
            a1.x = eA[4]*invA; a1.y = eA[5]*invA;  a1.z = eA[6]*invA;  a1.w = eA[7]*invA;
            a2.x = eA[8]*invA; a2.y = eA[9]*invA;  a2.z = eA[10]*invA; a2.w = eA[11]*invA;
            *(float4*)(ao)     = a0;
            *(float4*)(ao + 4) = a1;
            *(float4*)(ao + 8) = a2;
        }
    } else {
        #pragma unroll
        for (int j = 0; j < 12; ++j) eA[j] = 0.f;
    }

    // --- softmax B: window c-1 (this Q row acts as its row qq+6), over s[0..11] ---
    float eB[12], invB = 0.f;
    if (hasB) {
        float mxB = s[0];
        #pragma unroll
        for (int j = 1; j < 12; ++j) mxB = fmaxf(mxB, s[j]);
        float sumB = 0.f;
        #pragma unroll
        for (int j = 0; j < 12; ++j) { eB[j] = __expf((s[j] - mxB) * 0.125f); sumB += eB[j]; }
        invB = 1.0f / sumB;
    } else {
        #pragma unroll
        for (int j = 0; j < 12; ++j) eB[j] = 0.f;
    }

    // --- fused PV over all 18 tile rows with combined overlap-add weights ---
    if (qq < 6) {
        float4 xo0 = make_float4(0.f,0.f,0.f,0.f), xo1 = xo0, xo2 = xo0, xo3 = xo0;
        #pragma unroll
        for (int kt = 0; kt < 18; ++kt) {
            const float wa = (kt >= 6) ? eA[kt - 6] * invA : 0.f;
            const float wb = (kt < 12) ? eB[kt] * invB : 0.f;
            const float wk = scale * (wa + wb);
            const float* vp = &Vs[w][kt][ks * 16];
            const float4 v0 = *(const float4*)(vp);
            const float4 v1 = *(const float4*)(vp + 4);
            const float4 v2 = *(const float4*)(vp + 8);
            const float4 v3 = *(const float4*)(vp + 12);
            xo0.x += wk*v0.x; xo0.y += wk*v0.y; xo0.z += wk*v0.z; xo0.w += wk*v0.w;
            xo1.x += wk*v1.x; xo1.y += wk*v1.y; xo1.z += wk*v1.z; xo1.w += wk*v1.w;
            xo2.x += wk*v2.x; xo2.y += wk*v2.y; xo2.z += wk*v2.z; xo2.w += wk*v2.w;
            xo3.x += wk*v3.x; xo3.y += wk*v3.y; xo3.z += wk*v3.z; xo3.w += wk*v3.w;
        }
        // combined chunk row -> xout[b, c*6+qq, h*64 ..] (z buffer; K2b rewrites in place)
        float* xp = xout + ((size_t)b * L_ + (c * 6 + qq)) * DM + h * 64 + ks * 16;
        *(float4*)(xp)      = xo0;
        *(float4*)(xp + 4)  = xo1;
        *(float4*)(xp + 8)  = xo2;
        *(float4*)(xp + 12) = xo3;
    }
}

// ---------------------------------------------------------------------------
// K2b: residual + LayerNorm, streaming. Wave = row (512 floats, 8/lane).
// Reads xout (= z buffer) row, adds residual, LN, overwrites the SAME row
// (same wave reads then writes -> no race). Expressions identical to R3.
// ---------------------------------------------------------------------------
__global__ __launch_bounds__(512) void ln_kernel(
    const float* __restrict__ qres, const float* __restrict__ gamma,
    const float* __restrict__ beta, float* __restrict__ z)
{
    const int row = blockIdx.x * 8 + (threadIdx.x >> 6);   // 0..16367
    const int lane = threadIdx.x & 63;
    const int cc = lane * 8;

    float* xp = z + (size_t)row * DM + cc;
    float4 xa = *(const float4*)(xp);
    float4 xb = *(const float4*)(xp + 4);
    const float* qr = qres + (size_t)row * DM + cc;
    const float4 ra  = *(const float4*)qr;
    const float4 rb2 = *(const float4*)(qr + 4);
    xa.x += ra.x;  xa.y += ra.y;  xa.z += ra.z;  xa.w += ra.w;
    xb.x += rb2.x; xb.y += rb2.y; xb.z += rb2.z; xb.w += rb2.w;

    float s1 = xa.x + xa.y + xa.z + xa.w + xb.x + xb.y + xb.z + xb.w;
    float s2 = xa.x*xa.x + xa.y*xa.y + xa.z*xa.z + xa.w*xa.w
             + xb.x*xb.x + xb.y*xb.y + xb.z*xb.z + xb.w*xb.w;
    #pragma unroll
    for (int off = 1; off < 64; off <<= 1) {
        s1 += __shfl_xor(s1, off, 64);
        s2 += __shfl_xor(s2, off, 64);
    }
    const float mu  = s1 * (1.0f / 512.0f);
    const float var = s2 * (1.0f / 512.0f) - mu * mu;
    const float inv = 1.0f / sqrtf(var + EPS_);

    const float4 ga = *(const float4*)(gamma + cc);
    const float4 gb = *(const float4*)(gamma + cc + 4);
    const float4 ba = *(const float4*)(beta + cc);
    const float4 bb = *(const float4*)(beta + cc + 4);
    float4 oa, ob;
    oa.x = (xa.x - mu) * inv * ga.x + ba.x;
    oa.y = (xa.y - mu) * inv * ga.y + ba.y;
    oa.z = (xa.z - mu) * inv * ga.z + ba.z;
    oa.w = (xa.w - mu) * inv * ga.w + ba.w;
    ob.x = (xb.x - mu) * inv * gb.x + bb.x;
    ob.y = (xb.y - mu) * inv * gb.y + bb.y;
    ob.z = (xb.z - mu) * inv * gb.z + bb.z;
    ob.w = (xb.w - mu) * inv * gb.w + bb.w;
    *(float4*)(xp)     = oa;
    *(float4*)(xp + 4) = ob;
}

extern "C" void kernel_launch(void* const* d_in, const int* in_sizes, int n_in,
                              void* d_out, int out_size, void* d_ws, size_t ws_size,
                              hipStream_t stream) {
    const float* q     = (const float*)d_in[0];
    const float* k     = (const float*)d_in[1];
    const float* v     = (const float*)d_in[2];
    const float* Wq    = (const float*)d_in[3];
    const float* Wk    = (const float*)d_in[4];
    const float* Wv    = (const float*)d_in[5];
    const float* gamma = (const float*)d_in[6];
    const float* beta  = (const float*)d_in[7];

    float* z    = (float*)d_out;
    float* attn = (float*)d_out + Z_ELEMS;

    // Workspace: Qf fp32 (33.5 MB) + Kf fp32 (33.5 MB) + Vh bf16 (16.8 MB)
    const size_t plane = (size_t)B_ * H_ * L_ * 64;   // 8,380,416 elements
    float* Qf = (float*)d_ws;
    float* Kf = Qf + plane;
    u16*  Vh  = (u16*)(Kf + plane);

    proj_kernel<<<dim3(512, 3, 1), 256, 0, stream>>>(q, k, v, Wq, Wk, Wv, Qf, Kf, Vh);
    attn_kernel<<<dim3(NC, B_, 2), 256, 0, stream>>>(Qf, Kf, Vh, attn, z);
    ln_kernel<<<dim3(2046, 1, 1), 512, 0, stream>>>(q, gamma, beta, z);
}

// Round 6
// 227.108 us; speedup vs baseline: 2.9731x; 1.1195x over previous
//
#include <hip/hip_runtime.h>
#include <math.h>

#define B_    4
#define L_    4092
#define H_    8
#define DM    512
#define WS_   12
#define NW    681
#define NC    682            // 6-row output chunks per (b,h); L = 6*682
#define NC2   341            // chunk PAIRS (682 = 2*341)
#define EPS_  1e-5f
#define Z_ELEMS (B_*L_*DM)   // 8,380,416

typedef unsigned short u16;
typedef __attribute__((ext_vector_type(8))) short short8;
typedef __attribute__((ext_vector_type(4))) float floatx4;

__device__ __forceinline__ u16 f2bf(float f) {
    union { float f; unsigned u; } x; x.f = f;
    unsigned u = x.u;
    return (u16)((u + 0x7FFFu + ((u >> 16) & 1u)) >> 16);
}
__device__ __forceinline__ float bf2f(u16 h) {
    union { unsigned u; float f; } x; x.u = ((unsigned)h) << 16; return x.f;
}
// Dekker-style bf16 split: v = hi + lo + eps, |eps| <= 2^-18 |v|.
// (v - bf2f(hi)) is exact fp32 (Sterbenz: hi within 2^-9 of v); not foldable
// by fast-math (hi round-trips through integer ops).
__device__ __forceinline__ void pack8_hl(float4 a, float4 b, short8& hi, short8& lo) {
    float v[8] = {a.x, a.y, a.z, a.w, b.x, b.y, b.z, b.w};
    #pragma unroll
    for (int i = 0; i < 8; ++i) {
        u16 h = f2bf(v[i]);
        hi[i] = (short)h;
        lo[i] = (short)f2bf(v[i] - bf2f(h));
    }
}

// ---------------------------------------------------------------------------
// K1: projection GEMM via hi/lo bf16 MFMA, fp32 Q/K outputs.
// R5 diagnosis: the fp32-VALU version is LDS-return-bus bound (64 broadcast
// ds_read_b128 x ~12cy = 768cy per quad vs 560cy VALU -> VALUBusy 71%,
// 84 µs) and structurally cannot beat ~60 µs. MFMA moves operand delivery
// into registers. Precision: X and W Dekker-split into bf16 hi/lo; 3 product
// pairs (hh + hl + lh; ll ~ 2^-18 dropped) -> Q,K accurate to ~1e-5 and
// STORED FP32 -> score chain keeps R5-grade numerics. V stored bf16
// (workspace stays 83.8 MB = proven mapped). K2's score path is unchanged
// R5 code, so absmax is the hi/lo diagnostic: ~0.031 = works, ~0.11 = broken.
// Layout identical to the session-proven MFMA proj: A-frag row m=lane&15,
// k = q3*8+j (+32 for a1); B-frag nt holds W rows 4m+nt -> lane m's accs are
// output cols 4m..4m+3; C/D row = q3*4+reg.
// ---------------------------------------------------------------------------
__global__ __launch_bounds__(256) void proj_kernel(
    const float* __restrict__ q, const float* __restrict__ k, const float* __restrict__ v,
    const float* __restrict__ Wq, const float* __restrict__ Wk, const float* __restrict__ Wv,
    float* __restrict__ Qf, float* __restrict__ Kf, u16* __restrict__ Vh)
{
    const int tensor = blockIdx.y;
    const float* __restrict__ X = (tensor == 0) ? q  : (tensor == 1) ? k  : v;
    const float* __restrict__ W = (tensor == 0) ? Wq : (tensor == 1) ? Wk : Wv;
    float* __restrict__ Yf      = (tensor == 0) ? Qf : Kf;
    const bool isV = (tensor == 2);

    const int t = threadIdx.x, lane = t & 63, wv = t >> 6;
    const int m = lane & 15, q3 = lane >> 4;

    short8 wfh[4][2], wfl[4][2];
    #pragma unroll
    for (int nt = 0; nt < 4; ++nt)
        #pragma unroll
        for (int kc = 0; kc < 2; ++kc) {
            const float* wp = W + (4 * m + nt) * 64 + kc * 32 + q3 * 8;
            pack8_hl(*(const float4*)wp, *(const float4*)(wp + 4), wfh[nt][kc], wfl[nt][kc]);
        }

    const int waveId = blockIdx.x * 4 + wv;        // 0..2047
    for (int tile = waveId; tile < 8184; tile += 2048) {
        const int rbase = tile * 16;
        const int r = rbase + m;
        const int bh = r / L_;
        const int l = r - bh * L_;
        const int b = bh >> 3, h = bh & 7;
        const float* xp = X + (((size_t)b * L_ + l) * H_ + h) * 64;
        short8 a0h, a0l, a1h, a1l;
        pack8_hl(*(const float4*)(xp + q3 * 8),      *(const float4*)(xp + q3 * 8 + 4),      a0h, a0l);
        pack8_hl(*(const float4*)(xp + 32 + q3 * 8), *(const float4*)(xp + 32 + q3 * 8 + 4), a1h, a1l);

        floatx4 acc[4];
        #pragma unroll
        for (int nt = 0; nt < 4; ++nt) {
            floatx4 c = {0.f, 0.f, 0.f, 0.f};
            c = __builtin_amdgcn_mfma_f32_16x16x32_bf16(a0h, wfh[nt][0], c, 0, 0, 0);
            c = __builtin_amdgcn_mfma_f32_16x16x32_bf16(a1h, wfh[nt][1], c, 0, 0, 0);
            c = __builtin_amdgcn_mfma_f32_16x16x32_bf16(a0h, wfl[nt][0], c, 0, 0, 0);
            c = __builtin_amdgcn_mfma_f32_16x16x32_bf16(a0l, wfh[nt][0], c, 0, 0, 0);
            c = __builtin_amdgcn_mfma_f32_16x16x32_bf16(a1h, wfl[nt][1], c, 0, 0, 0);
            c = __builtin_amdgcn_mfma_f32_16x16x32_bf16(a1l, wfh[nt][1], c, 0, 0, 0);
            acc[nt] = c;
        }
        #pragma unroll
        for (int reg = 0; reg < 4; ++reg) {
            const int row = rbase + q3 * 4 + reg;
            if (!isV) {
                float4 o4;
                o4.x = acc[0][reg]; o4.y = acc[1][reg];
                o4.z = acc[2][reg]; o4.w = acc[3][reg];
                *(float4*)(Yf + (size_t)row * 64 + 4 * m) = o4;
            } else {
                ushort4 o4;
                o4.x = f2bf(acc[0][reg]); o4.y = f2bf(acc[1][reg]);
                o4.z = f2bf(acc[2][reg]); o4.w = f2bf(acc[3][reg]);
                *(ushort4*)(Vh + (size_t)row * 64 + 4 * m) = o4;
            }
        }
    }
}

// ---------------------------------------------------------------------------
// K2a: fused window attention + overlap-add, S=2 super-chunk blocks.
// Block = (chunk-pair c2, batch b, head-group hg), 256 threads = 4 heads.
// Stages 24 K/V rows ONCE for two consecutive chunks (vs 2x18) -> staging
// LDS-bus + global K/V traffic -33%, half the blocks. LDS 49.2 KB -> 3
// blocks/CU. Sub-chunk c = 2*c2+j reads staged rows [6j .. 6j+17].
// Dot/softmax/PV expressions verbatim from R5 -> bit-identical output.
// One barrier; no LDS writes after it (j-loop is read-only on LDS).
// ---------------------------------------------------------------------------
__global__ __launch_bounds__(256, 3) void attn_kernel(
    const float* __restrict__ Qf, const float* __restrict__ Kf, const u16* __restrict__ Vh,
    float* __restrict__ attn, float* __restrict__ xout)
{
    __shared__ alignas(16) float Ks[4][24][64];   // 24.6 KB
    __shared__ alignas(16) float Vs[4][24][64];   // 24.6 KB

    const int c2 = blockIdx.x, b = blockIdx.y, hg = blockIdx.z;
    const int t = threadIdx.x, lane = t & 63, w = t >> 6;   // w = head-in-group
    const int h = hg * 4 + w;
    const int qq = lane >> 2, ks = lane & 3;
    const int bh = b * 8 + h;
    const int lbase = c2 * 12 - 6;                 // staged row 0 -> global row lbase

    // --- stage K (fp32) + V (bf16->fp32) for 4 heads x 24 rows, zero-fill OOB ---
    for (int i = t; i < 1536; i += 256) {          // 1536 = 4 heads * 24 rows * 16 float4
        const int hh  = i / 384;
        const int rem = i - hh * 384;
        const int rr  = rem >> 4;
        const int cc  = (rem & 15) * 4;
        const int l = lbase + rr;
        float4 kf4 = make_float4(0.f, 0.f, 0.f, 0.f);
        float4 vf4 = make_float4(0.f, 0.f, 0.f, 0.f);
        if (l >= 0 && l < L_) {
            const size_t base = ((size_t)(b * 8 + hg * 4 + hh) * L_ + l) * 64 + cc;
            kf4 = *(const float4*)(Kf + base);
            const ushort4 u4 = *(const ushort4*)(Vh + base);
            vf4.x = bf2f(u4.x); vf4.y = bf2f(u4.y); vf4.z = bf2f(u4.z); vf4.w = bf2f(u4.w);
        }
        *(float4*)&Ks[hh][rr][cc] = kf4;
        *(float4*)&Vs[hh][rr][cc] = vf4;
    }
    __syncthreads();

    #pragma unroll
    for (int j = 0; j < 2; ++j) {
        const int c = c2 * 2 + j;
        const bool hasA = (c < NW), hasB = (c > 0);     // uniform per j-iteration
        const float scale = (hasA && hasB) ? 0.5f : 1.0f;
        const int koff = 6 * j;                          // staged-row offset of this chunk

        // Q segment for global row c*6+qq (zeros on invalid lanes -> s==0, finite)
        float4 qs0, qs1, qs2, qs3;
        const int qmax = hasA ? 12 : 6;
        if (qq < qmax) {
            const float* qp = Qf + ((size_t)bh * L_ + (c * 6 + qq)) * 64 + ks * 16;
            qs0 = *(const float4*)(qp);     qs1 = *(const float4*)(qp + 4);
            qs2 = *(const float4*)(qp + 8); qs3 = *(const float4*)(qp + 12);
        } else {
            qs0 = qs1 = qs2 = qs3 = make_float4(0.f, 0.f, 0.f, 0.f);
        }

        // --- unified dot pass vs the chunk's 18 staged K rows ---
        float s[18];
        #pragma unroll
        for (int kt = 0; kt < 18; ++kt) {
            const float* kp = &Ks[w][koff + kt][ks * 16];
            const float4 k0 = *(const float4*)(kp);
            const float4 k1 = *(const float4*)(kp + 4);
            const float4 k2 = *(const float4*)(kp + 8);
            const float4 k3 = *(const float4*)(kp + 12);
            s[kt] = qs0.x*k0.x + qs0.y*k0.y + qs0.z*k0.z + qs0.w*k0.w
                  + qs1.x*k1.x + qs1.y*k1.y + qs1.z*k1.z + qs1.w*k1.w
                  + qs2.x*k2.x + qs2.y*k2.y + qs2.z*k2.z + qs2.w*k2.w
                  + qs3.x*k3.x + qs3.y*k3.y + qs3.z*k3.z + qs3.w*k3.w;
        }
        #pragma unroll
        for (int kt = 0; kt < 18; ++kt) {
            s[kt] += __shfl_xor(s[kt], 1);
            s[kt] += __shfl_xor(s[kt], 2);
        }

        // --- softmax A: window c, over s[6..17] ---
        float eA[12], invA = 0.f;
        if (hasA) {
            float mxA = s[6];
            #pragma unroll
            for (int jj = 1; jj < 12; ++jj) mxA = fmaxf(mxA, s[6 + jj]);
            float sumA = 0.f;
            #pragma unroll
            for (int jj = 0; jj < 12; ++jj) { eA[jj] = __expf((s[6 + jj] - mxA) * 0.125f); sumA += eA[jj]; }
            invA = 1.0f / sumA;
            if (ks == 0 && qq < 12) {
                float* ao = attn + ((size_t)bh * NW + c) * 144 + qq * 12;
                float4 a0, a1, a2;
                a0.x = eA[0]*invA; a0.y = eA[1]*invA;  a0.z = eA[2]*invA;  a0.w = eA[3]*invA;
                a1.x = eA[4]*invA; a1.y = eA[5]*invA;  a1.z = eA[6]*invA;  a1.w = eA[7]*invA;
                a2.x = eA[8]*invA; a2.y = eA[9]*invA;  a2.z = eA[10]*invA; a2.w = eA[11]*invA;
                *(float4*)(ao)     = a0;
                *(float4*)(ao + 4) = a1;
                *(float4*)(ao + 8) = a2;
            }
        } else {
            #pragma unroll
            for (int jj = 0; jj < 12; ++jj) eA[jj] = 0.f;
        }

        // --- softmax B: window c-1 (this Q row acts as its row qq+6), s[0..11] ---
        float eB[12], invB = 0.f;
        if (hasB) {
            float mxB = s[0];
            #pragma unroll
            for (int jj = 1; jj < 12; ++jj) mxB = fmaxf(mxB, s[jj]);
            float sumB = 0.f;
            #pragma unroll
            for (int jj = 0; jj < 12; ++jj) { eB[jj] = __expf((s[jj] - mxB) * 0.125f); sumB += eB[jj]; }
            invB = 1.0f / sumB;
        } else {
            #pragma unroll
            for (int jj = 0; jj < 12; ++jj) eB[jj] = 0.f;
        }

        // --- fused PV over the chunk's 18 rows with combined overlap-add weights ---
        if (qq < 6) {
            float4 xo0 = make_float4(0.f,0.f,0.f,0.f), xo1 = xo0, xo2 = xo0, xo3 = xo0;
            #pragma unroll
            for (int kt = 0; kt < 18; ++kt) {
                const float wa = (kt >= 6) ? eA[kt - 6] * invA : 0.f;
                const float wb = (kt < 12) ? eB[kt] * invB : 0.f;
                const float wk = scale * (wa + wb);
                const float* vp = &Vs[w][koff + kt][ks * 16];
                const float4 v0 = *(const float4*)(vp);
                const float4 v1 = *(const float4*)(vp + 4);
                const float4 v2 = *(const float4*)(vp + 8);
                const float4 v3 = *(const float4*)(vp + 12);
                xo0.x += wk*v0.x; xo0.y += wk*v0.y; xo0.z += wk*v0.z; xo0.w += wk*v0.w;
                xo1.x += wk*v1.x; xo1.y += wk*v1.y; xo1.z += wk*v1.z; xo1.w += wk*v1.w;
                xo2.x += wk*v2.x; xo2.y += wk*v2.y; xo2.z += wk*v2.z; xo2.w += wk*v2.w;
                xo3.x += wk*v3.x; xo3.y += wk*v3.y; xo3.z += wk*v3.z; xo3.w += wk*v3.w;
            }
            float* xp = xout + ((size_t)b * L_ + (c * 6 + qq)) * DM + h * 64 + ks * 16;
            *(float4*)(xp)      = xo0;
            *(float4*)(xp + 4)  = xo1;
            *(float4*)(xp + 8)  = xo2;
            *(float4*)(xp + 12) = xo3;
        }
    }
}

// ---------------------------------------------------------------------------
// K2b: residual + LayerNorm, streaming. Wave = row (512 floats, 8/lane).
// Reads xout (= z buffer) row, adds residual, LN, overwrites the SAME row
// (same wave reads then writes -> no race). Expressions identical to R5.
// ---------------------------------------------------------------------------
__global__ __launch_bounds__(512) void ln_kernel(
    const float* __restrict__ qres, const float* __restrict__ gamma,
    const float* __restrict__ beta, float* __restrict__ z)
{
    const int row = blockIdx.x * 8 + (threadIdx.x >> 6);   // 0..16367
    const int lane = threadIdx.x & 63;
    const int cc = lane * 8;

    float* xp = z + (size_t)row * DM + cc;
    float4 xa = *(const float4*)(xp);
    float4 xb = *(const float4*)(xp + 4);
    const float* qr = qres + (size_t)row * DM + cc;
    const float4 ra  = *(const float4*)qr;
    const float4 rb2 = *(const float4*)(qr + 4);
    xa.x += ra.x;  xa.y += ra.y;  xa.z += ra.z;  xa.w += ra.w;
    xb.x += rb2.x; xb.y += rb2.y; xb.z += rb2.z; xb.w += rb2.w;

    float s1 = xa.x + xa.y + xa.z + xa.w + xb.x + xb.y + xb.z + xb.w;
    float s2 = xa.x*xa.x + xa.y*xa.y + xa.z*xa.z + xa.w*xa.w
             + xb.x*xb.x + xb.y*xb.y + xb.z*xb.z + xb.w*xb.w;
    #pragma unroll
    for (int off = 1; off < 64; off <<= 1) {
        s1 += __shfl_xor(s1, off, 64);
        s2 += __shfl_xor(s2, off, 64);
    }
    const float mu  = s1 * (1.0f / 512.0f);
    const float var = s2 * (1.0f / 512.0f) - mu * mu;
    const float inv = 1.0f / sqrtf(var + EPS_);

    const float4 ga = *(const float4*)(gamma + cc);
    const float4 gb = *(const float4*)(gamma + cc + 4);
    const float4 ba = *(const float4*)(beta + cc);
    const float4 bb = *(const float4*)(beta + cc + 4);
    float4 oa, ob;
    oa.x = (xa.x - mu) * inv * ga.x + ba.x;
    oa.y = (xa.y - mu) * inv * ga.y + ba.y;
    oa.z = (xa.z - mu) * inv * ga.z + ba.z;
    oa.w = (xa.w - mu) * inv * ga.w + ba.w;
    ob.x = (xb.x - mu) * inv * gb.x + bb.x;
    ob.y = (xb.y - mu) * inv * gb.y + bb.y;
    ob.z = (xb.z - mu) * inv * gb.z + bb.z;
    ob.w = (xb.w - mu) * inv * gb.w + bb.w;
    *(float4*)(xp)     = oa;
    *(float4*)(xp + 4) = ob;
}

extern "C" void kernel_launch(void* const* d_in, const int* in_sizes, int n_in,
                              void* d_out, int out_size, void* d_ws, size_t ws_size,
                              hipStream_t stream) {
    const float* q     = (const float*)d_in[0];
    const float* k     = (const float*)d_in[1];
    const float* v     = (const float*)d_in[2];
    const float* Wq    = (const float*)d_in[3];
    const float* Wk    = (const float*)d_in[4];
    const float* Wv    = (const float*)d_in[5];
    const float* gamma = (const float*)d_in[6];
    const float* beta  = (const float*)d_in[7];

    float* z    = (float*)d_out;
    float* attn = (float*)d_out + Z_ELEMS;

    // Workspace: Qf fp32 (33.5 MB) + Kf fp32 (33.5 MB) + Vh bf16 (16.8 MB)
    // = 83.8 MB (proven mapped since R2).
    const size_t plane = (size_t)B_ * H_ * L_ * 64;   // 8,380,416 elements
    float* Qf = (float*)d_ws;
    float* Kf = Qf + plane;
    u16*  Vh  = (u16*)(Kf + plane);

    proj_kernel<<<dim3(512, 3, 1), 256, 0, stream>>>(q, k, v, Wq, Wk, Wv, Qf, Kf, Vh);
    attn_kernel<<<dim3(NC2, B_, 2), 256, 0, stream>>>(Qf, Kf, Vh, attn, z);
    ln_kernel<<<dim3(2046, 1, 1), 512, 0, stream>>>(q, gamma, beta, z);
}